// Round 8
// baseline (367.582 us; speedup 1.0000x reference)
//
#include <hip/hip_runtime.h>
#include <hip/hip_fp16.h>
#include <math.h>

#define NEG_SLOPE 0.2f
typedef unsigned short ushort_t;
typedef unsigned int uint_t;

#if defined(__has_builtin)
#if __has_builtin(__builtin_amdgcn_cvt_pk_fp8_f32) && __has_builtin(__builtin_amdgcn_cvt_f32_fp8)
#define HAVE_FP8_CVT 1
#endif
#endif

// e4m3 encode x4 -> one uint (byte h = ae[h])
__device__ __forceinline__ uint_t pack_fp8x4(float a, float b, float c, float d) {
#ifdef HAVE_FP8_CVT
  int v = __builtin_amdgcn_cvt_pk_fp8_f32(a, b, 0, false);
  v = __builtin_amdgcn_cvt_pk_fp8_f32(c, d, v, true);
  return (uint_t)v;
#else
  auto enc = [](float x) -> uint_t {
    uint_t bb = __float_as_uint(x);
    uint_t s = (bb >> 24) & 0x80u;
    int e = (int)((bb >> 23) & 0xffu);
    uint_t m = (bb >> 20) & 7u;
    m += (bb >> 19) & 1u;
    if (m > 7u) { m = 0u; e++; }
    e = e - 127 + 7;
    if (e <= 0) return s;
    if (e > 15) return s | 0x7eu;
    return s | ((uint_t)e << 3) | m;
  };
  return enc(a) | (enc(b) << 8) | (enc(c) << 16) | (enc(d) << 24);
#endif
}

// decode byte (w >> shift) & 0xff as e4m3 -> float
__device__ __forceinline__ float unpack_fp8(uint_t w, int shift) {
#ifdef HAVE_FP8_CVT
  return __builtin_amdgcn_cvt_f32_fp8((int)(w >> shift), 0);
#else
  uint_t b = (w >> shift) & 0xffu;
  uint_t s = (b & 0x80u) << 24;
  uint_t em = b & 0x7fu;
  uint_t f = s | ((em << 20) + (120u << 23));
  return (em == 0u) ? __uint_as_float(s) : __uint_as_float(f);
#endif
}

// ---------------- K_prep: fused {int64-detect | v_edge | head = -1}
__global__ void k_prep(const int* __restrict__ ei, int* __restrict__ is64,
                       int* __restrict__ head, int N,
                       const float* __restrict__ W_edge, const float* __restrict__ att_edge,
                       float* __restrict__ v_edge) {
  int b = blockIdx.x, t = threadIdx.x;
  if (b == 0) {
    __shared__ int any;
    if (t == 0) any = 0;
    __syncthreads();
    if (ei[2 * t + 1] != 0) atomicOr(&any, 1);
    __syncthreads();
    if (t == 0) *is64 = (any == 0) ? 1 : 0;
  } else if (b == 1) {
    if (t < 64) {
      int h = t >> 4, j = t & 15;
      float s = 0.f;
#pragma unroll
      for (int c = 0; c < 32; ++c) s += W_edge[j * 128 + h * 32 + c] * att_edge[h * 32 + c];
      v_edge[t] = s;
    }
  } else {
    int i = (b - 2) * 256 + t;
    if (i < N) head[i] = -1;
  }
}

// ---------------- K_build: per-node linked list of in-edges.
// next[i] coalesced; atomicExch on head is the ONLY random op.
__global__ void k_build(const int* __restrict__ ei, const int* __restrict__ is64,
                        int* __restrict__ head, int* __restrict__ next, int E) {
  int i = blockIdx.x * blockDim.x + threadIdx.x;
  if (i >= E) return;
  int dst = (*is64) ? ei[2 * (E + i)] : ei[E + i];
  next[i] = atomicExch(&head[dst], i);
}

// ---------------- K1: x_l = x @ W (f32 compute), fp16 store + fused a_src/a_dst epilogue
__global__ __launch_bounds__(256) void k1_xl(
    const float* __restrict__ x, const float* __restrict__ W,
    const float* __restrict__ att_src, const float* __restrict__ att_dst,
    ushort_t* __restrict__ x_l_h, float* __restrict__ a_src, float* __restrict__ a_dst, int N) {
  __shared__ float Wc[32 * 128];   // 16 KB
  __shared__ float Xc[32 * 64];    // 8 KB (transposed: Xc[k][r])
  const int t = threadIdx.x;
  const int tcol = t & 31;         // cols tcol*4 .. +3   (head h = tcol>>3)
  const int trow = t >> 5;         // rows trow*8 .. +7
  const int row0 = blockIdx.x * 64;
  const int r = t & 63, kq = t >> 6;
  const float4 aw_s = *(const float4*)&att_src[tcol * 4];
  const float4 aw_d = *(const float4*)&att_dst[tcol * 4];
  float acc[8][4];
#pragma unroll
  for (int i = 0; i < 8; ++i) { acc[i][0] = acc[i][1] = acc[i][2] = acc[i][3] = 0.f; }

  for (int kc = 0; kc < 4; ++kc) {
    float4 wreg[4];
#pragma unroll
    for (int q = 0; q < 4; ++q) wreg[q] = *(const float4*)&W[kc * 4096 + (q * 256 + t) * 4];
    float xs8[8];
    int grow = row0 + r;
    if (grow < N) {
      *(float4*)&xs8[0] = *(const float4*)&x[grow * 128 + kc * 32 + kq * 8];
      *(float4*)&xs8[4] = *(const float4*)&x[grow * 128 + kc * 32 + kq * 8 + 4];
    } else {
#pragma unroll
      for (int q = 0; q < 8; ++q) xs8[q] = 0.f;
    }
    __syncthreads();   // previous chunk's compute done
#pragma unroll
    for (int q = 0; q < 4; ++q) *(float4*)&Wc[(q * 256 + t) * 4] = wreg[q];
#pragma unroll
    for (int q = 0; q < 8; ++q) Xc[(kq * 8 + q) * 64 + r] = xs8[q];
    __syncthreads();
#pragma unroll
    for (int kk = 0; kk < 32; ++kk) {
      float4 wv = *(const float4*)&Wc[kk * 128 + tcol * 4];
      float xr[8];
      *(float4*)&xr[0] = *(const float4*)&Xc[kk * 64 + trow * 8];
      *(float4*)&xr[4] = *(const float4*)&Xc[kk * 64 + trow * 8 + 4];
#pragma unroll
      for (int ri = 0; ri < 8; ++ri) {
        acc[ri][0] += xr[ri] * wv.x;
        acc[ri][1] += xr[ri] * wv.y;
        acc[ri][2] += xr[ri] * wv.z;
        acc[ri][3] += xr[ri] * wv.w;
      }
    }
  }
#pragma unroll
  for (int ri = 0; ri < 8; ++ri) {
    int grow = row0 + trow * 8 + ri;
    float asp = acc[ri][0] * aw_s.x + acc[ri][1] * aw_s.y + acc[ri][2] * aw_s.z + acc[ri][3] * aw_s.w;
    float adp = acc[ri][0] * aw_d.x + acc[ri][1] * aw_d.y + acc[ri][2] * aw_d.z + acc[ri][3] * aw_d.w;
#pragma unroll
    for (int m = 1; m < 8; m <<= 1) { asp += __shfl_xor(asp, m); adp += __shfl_xor(adp, m); }
    if (grow < N) {
      __half2 h0 = __floats2half2_rn(acc[ri][0], acc[ri][1]);
      __half2 h1 = __floats2half2_rn(acc[ri][2], acc[ri][3]);
      uint2 u; u.x = *(uint_t*)&h0; u.y = *(uint_t*)&h1;
      *(uint2*)&x_l_h[(size_t)grow * 128 + tcol * 4] = u;
      if ((tcol & 7) == 0) {
        a_src[grow * 4 + (tcol >> 3)] = asp;
        a_dst[grow * 4 + (tcol >> 3)] = adp;
      }
    }
  }
}

// ---------------- K_rec: FULLY COALESCED per-edge record build at original edge id.
// Reads edge_attr streamed, a_src/a_dst gathers (L2-resident), computes
// p = exp(leaky(as+ad+ae)); writes rec[i] = {half2 p01, half2 p23, src, fp8x4 ae}.
__global__ __launch_bounds__(256) void k_rec(
    const int* __restrict__ ei, const int* __restrict__ is64,
    const float* __restrict__ edge_attr, const float* __restrict__ v_edge,
    const float* __restrict__ a_src, const float* __restrict__ a_dst,
    int4* __restrict__ rec, int E) {
  __shared__ float ve[64];
  int t = threadIdx.x;
  if (t < 64) ve[t] = v_edge[t];
  __syncthreads();
  int i = blockIdx.x * 256 + t;
  if (i >= E) return;
  int f = *is64;
  int src = f ? ei[2 * i] : ei[i];
  int dst = f ? ei[2 * (E + i)] : ei[E + i];
  float a16[16];
  *(float4*)&a16[0]  = *(const float4*)&edge_attr[(size_t)i * 16];
  *(float4*)&a16[4]  = *(const float4*)&edge_attr[(size_t)i * 16 + 4];
  *(float4*)&a16[8]  = *(const float4*)&edge_attr[(size_t)i * 16 + 8];
  *(float4*)&a16[12] = *(const float4*)&edge_attr[(size_t)i * 16 + 12];
  float ae[4];
#pragma unroll
  for (int h = 0; h < 4; ++h) {
    float s = 0.f;
#pragma unroll
    for (int j = 0; j < 16; ++j) s += a16[j] * ve[h * 16 + j];
    ae[h] = s;
  }
  float4 as4 = *(const float4*)&a_src[(size_t)src * 4];
  float4 ad4 = *(const float4*)&a_dst[(size_t)dst * 4];
  const float* asp = (const float*)&as4;
  const float* adp = (const float*)&ad4;
  float p[4];
#pragma unroll
  for (int h = 0; h < 4; ++h) {
    float g = asp[h] + adp[h] + ae[h];
    g = fmaxf(g, NEG_SLOPE * g);   // leaky_relu (slope < 1)
    p[h] = __expf(g);
  }
  __half2 p01 = __floats2half2_rn(p[0], p[1]);
  __half2 p23 = __floats2half2_rn(p[2], p[3]);
  uint_t aepk = pack_fp8x4(ae[0], ae[1], ae[2], ae[3]);
  int4 r; r.x = *(int*)&p01; r.y = *(int*)&p23; r.z = src; r.w = (int)aepk;
  rec[i] = r;   // coalesced!
}

// ---------------- K34: chain-walk aggregation. One wave serves 4 nodes
// (4 independent chases -> 4-way MLP on the serial next[] dependency).
// rec/next loads are wave-uniform (scalar path); lane covers cols {2l,2l+1}.
// out = (sum p*x + pl*x_node) / (sum p + pl) + bias; pl from mean(ae) fp8.
__global__ __launch_bounds__(256) void k34_chase(
    const int4* __restrict__ rec, const int* __restrict__ next,
    const int* __restrict__ head, const uint_t* __restrict__ xu,
    const float* __restrict__ a_src, const float* __restrict__ a_dst,
    const float* __restrict__ bias, float* __restrict__ out, int N) {
  int lane = threadIdx.x & 63;
  int wv = blockIdx.x * 4 + (threadIdx.x >> 6);
  int n0 = wv * 4;
  if (n0 >= N) return;
  int h = lane >> 4;
  int hs16 = (h & 1) << 4;
  int hs8  = h << 3;
  float ax0 = 0.f, ay0 = 0.f, dn0 = 0.f, se0 = 0.f;
  float ax1 = 0.f, ay1 = 0.f, dn1 = 0.f, se1 = 0.f;
  float ax2 = 0.f, ay2 = 0.f, dn2 = 0.f, se2 = 0.f;
  float ax3 = 0.f, ay3 = 0.f, dn3 = 0.f, se3 = 0.f;
  int c0 = 0, c1 = 0, c2 = 0, c3 = 0;
  int e0 = __builtin_amdgcn_readfirstlane(head[n0]);
  int e1 = (n0 + 1 < N) ? __builtin_amdgcn_readfirstlane(head[n0 + 1]) : -1;
  int e2 = (n0 + 2 < N) ? __builtin_amdgcn_readfirstlane(head[n0 + 2]) : -1;
  int e3 = (n0 + 3 < N) ? __builtin_amdgcn_readfirstlane(head[n0 + 3]) : -1;

  auto step = [&](int& e, float& ax, float& ay, float& dn, float& se, int& ct) {
    if (e >= 0) {
      int en = next[e];
      int4 u = rec[e];
      uint_t v = xu[((size_t)(uint_t)u.z << 6) + lane];
      uint_t w = (h & 2) ? (uint_t)u.y : (uint_t)u.x;
      float p = __half2float(__ushort_as_half((ushort_t)(w >> hs16)));
      dn += p;
      se += unpack_fp8((uint_t)u.w, hs8);
      ct++;
      float2 fx = __half22float2(*(const __half2*)&v);
      ax += p * fx.x; ay += p * fx.y;
      e = __builtin_amdgcn_readfirstlane(en);
    }
  };

  // FIX (R7): "any chain alive" condition only. The old `(e0|e1|e2|e3) != -1`
  // clause is -1 whenever ANY chain ends (OR with all-ones), exiting early and
  // dropping edges of the live chains.
  while (e0 >= 0 || e1 >= 0 || e2 >= 0 || e3 >= 0) {
    step(e0, ax0, ay0, dn0, se0, c0);
    step(e1, ax1, ay1, dn1, se1, c1);
    step(e2, ax2, ay2, dn2, se2, c2);
    step(e3, ax3, ay3, dn3, se3, c3);
  }

  auto fin = [&](int node, float ax, float ay, float dn, float se, int ct) {
    if (node >= N) return;
    float ad  = a_dst[(size_t)node * 4 + h];
    float asn = a_src[(size_t)node * 4 + h];
    float ic = 1.f / (float)(ct > 0 ? ct : 1);
    float gl = asn + ad + se * ic;
    gl = fmaxf(gl, NEG_SLOPE * gl);
    float pl = __expf(gl);
    float iv = 1.f / (dn + pl);
    uint_t vn = xu[((size_t)(uint_t)node << 6) + lane];
    float2 fn = __half22float2(*(const __half2*)&vn);
    float2 b2 = *(const float2*)&bias[2 * lane];
    float2 o;
    o.x = (ax + pl * fn.x) * iv + b2.x;
    o.y = (ay + pl * fn.y) * iv + b2.y;
    *(float2*)&out[(size_t)node * 128 + 2 * lane] = o;
  };
  fin(n0, ax0, ay0, dn0, se0, c0);
  fin(n0 + 1, ax1, ay1, dn1, se1, c1);
  fin(n0 + 2, ax2, ay2, dn2, se2, c2);
  fin(n0 + 3, ax3, ay3, dn3, se3, c3);
}

extern "C" void kernel_launch(void* const* d_in, const int* in_sizes, int n_in,
                              void* d_out, int out_size, void* d_ws, size_t ws_size,
                              hipStream_t stream) {
  const float* x        = (const float*)d_in[0];
  const int*   ei       = (const int*)  d_in[1];
  const float* eattr    = (const float*)d_in[2];
  const float* W        = (const float*)d_in[3];
  const float* W_edge   = (const float*)d_in[4];
  const float* att_src  = (const float*)d_in[5];
  const float* att_dst  = (const float*)d_in[6];
  const float* att_edge = (const float*)d_in[7];
  const float* bias     = (const float*)d_in[8];
  float* out = (float*)d_out;
  const int N = in_sizes[0] / 128;
  const int E = in_sizes[1] / 2;
  (void)n_in; (void)out_size; (void)ws_size;

  char* base = (char*)d_ws;
  size_t off = 0;
  auto take = [&](size_t bytes) -> void* {
    void* p = base + off;
    off = (off + bytes + 255) & ~(size_t)255;
    return p;
  };
  ushort_t* x_l_h = (ushort_t*)take((size_t)N * 128 * 2);
  float* a_src    = (float*)take((size_t)N * 4 * 4);
  float* a_dst    = (float*)take((size_t)N * 4 * 4);
  float* v_edge   = (float*)take(64 * 4);
  int4*  rec      = (int4*)take((size_t)E * 16);       // {p01, p23, src, ae_fp8x4}
  int*   head     = (int*)take((size_t)N * 4);
  int*   next     = (int*)take((size_t)E * 4);
  int*   is64     = (int*)take(4);

  const int nbh = (E + 255) / 256;

  hipLaunchKernelGGL(k_prep, dim3(2 + (N + 255) / 256), dim3(256), 0, stream,
                     ei, is64, head, N, W_edge, att_edge, v_edge);
  hipLaunchKernelGGL(k_build, dim3(nbh), dim3(256), 0, stream, ei, is64, head, next, E);
  hipLaunchKernelGGL(k1_xl, dim3((N + 63) / 64), dim3(256), 0, stream,
                     x, W, att_src, att_dst, x_l_h, a_src, a_dst, N);
  hipLaunchKernelGGL(k_rec, dim3(nbh), dim3(256), 0, stream,
                     ei, is64, eattr, v_edge, a_src, a_dst, rec, E);
  hipLaunchKernelGGL(k34_chase, dim3((N + 15) / 16), dim3(256), 0, stream,
                     rec, next, head, (const uint_t*)x_l_h, a_src, a_dst, bias, out, N);
}

// Round 9
// 267.801 us; speedup vs baseline: 1.3726x; 1.3726x over previous
//
#include <hip/hip_runtime.h>
#include <hip/hip_fp16.h>
#include <math.h>

#define NEG_SLOPE 0.2f
typedef unsigned short ushort_t;
typedef unsigned int uint_t;

// ---------------- K_prep: fused {int64-detect | v_edge | zero deg}
__global__ void k_prep(const int* __restrict__ ei, int* __restrict__ is64,
                       int* __restrict__ deg, int N,
                       const float* __restrict__ W_edge, const float* __restrict__ att_edge,
                       float* __restrict__ v_edge) {
  int b = blockIdx.x, t = threadIdx.x;
  if (b == 0) {
    __shared__ int any;
    if (t == 0) any = 0;
    __syncthreads();
    if (ei[2 * t + 1] != 0) atomicOr(&any, 1);
    __syncthreads();
    if (t == 0) *is64 = (any == 0) ? 1 : 0;
  } else if (b == 1) {
    if (t < 64) {
      int h = t >> 4, j = t & 15;
      float s = 0.f;
#pragma unroll
      for (int c = 0; c < 32; ++c) s += W_edge[j * 128 + h * 32 + c] * att_edge[h * 32 + c];
      v_edge[t] = s;
    }
  } else {
    int i = (b - 2) * 256 + t;
    if (i < N) deg[i] = 0;
  }
}

// ---------------- K2a: in-degree histogram + per-edge rank (atomic return value)
// Zero LDS, tiny VGPR -> max occupancy to hide atomic latency.
__global__ void k_hist(const int* __restrict__ ei, const int* __restrict__ is64,
                       int* __restrict__ deg, int* __restrict__ rank, int E) {
  int i = blockIdx.x * blockDim.x + threadIdx.x;
  if (i >= E) return;
  int dst = (*is64) ? ei[2 * (E + i)] : ei[E + i];
  rank[i] = atomicAdd(&deg[dst], 1);
}

// ---------------- 3-kernel exclusive scan over deg[N] (1024 elems/block)
__global__ void k_scan1(const int* __restrict__ deg, int* __restrict__ bsum, int N) {
  __shared__ int lds[256];
  int b = blockIdx.x, t = threadIdx.x;
  int base = b * 1024 + t * 4;
  int s = 0;
  if (base + 3 < N) {
    int4 v = *(const int4*)&deg[base];
    s = v.x + v.y + v.z + v.w;
  } else {
    for (int q = 0; q < 4; ++q) if (base + q < N) s += deg[base + q];
  }
  lds[t] = s; __syncthreads();
  for (int st = 128; st > 0; st >>= 1) {
    if (t < st) lds[t] += lds[t + st];
    __syncthreads();
  }
  if (t == 0) bsum[b] = lds[0];
}

__global__ void k_scan2(const int* __restrict__ bsum, int* __restrict__ boff, int NB) {
  __shared__ int lds[256];
  int t = threadIdx.x;
  int v = (t < NB) ? bsum[t] : 0;
  lds[t] = v;
  __syncthreads();
  for (int st = 1; st < 256; st <<= 1) {
    int add = (t >= st) ? lds[t - st] : 0;
    __syncthreads();
    lds[t] += add;
    __syncthreads();
  }
  if (t < NB) boff[t] = lds[t] - v;   // exclusive
}

__global__ void k_scan3(const int* __restrict__ deg, const int* __restrict__ boff,
                        int* __restrict__ offs, int N) {
  __shared__ int lds[256];
  int b = blockIdx.x, t = threadIdx.x;
  int base = b * 1024 + t * 4;
  int v[4]; int s = 0;
#pragma unroll
  for (int q = 0; q < 4; ++q) { v[q] = (base + q < N) ? deg[base + q] : 0; s += v[q]; }
  lds[t] = s;
  __syncthreads();
  for (int st = 1; st < 256; st <<= 1) {
    int add = (t >= st) ? lds[t - st] : 0;
    __syncthreads();
    lds[t] += add;
    __syncthreads();
  }
  int run = boff[b] + lds[t] - s;
#pragma unroll
  for (int q = 0; q < 4; ++q) {
    if (base + q < N) offs[base + q] = run;
    run += v[q];
  }
}

// ---------------- K1S: fused {dst-sorted scatter | x_l GEMM}.
// Scatter blocks FIRST (longer pole; latency-bound, VALU~4%), GEMM blocks after
// (VALU-bound) -> heterogeneous co-residency overlaps pipes (R4 evidence: -27us).
// Scatter writes ae-only records so it has NO dependency on the GEMM's outputs.
// Record: {half2 ae01, half2 ae23, src, pad} at dst-sorted position.
__global__ __launch_bounds__(256) void k1_scatter(
    const float* __restrict__ x, const float* __restrict__ W,
    const float* __restrict__ att_src, const float* __restrict__ att_dst,
    ushort_t* __restrict__ x_l_h, float* __restrict__ a_src, float* __restrict__ a_dst, int N,
    const int* __restrict__ ei, const int* __restrict__ is64,
    const int* __restrict__ rank, const int* __restrict__ offs,
    const float* __restrict__ edge_attr, const float* __restrict__ v_edge,
    int4* __restrict__ rec, int E, int nbs) {
  __shared__ float Wc[32 * 128];   // 16 KB (scatter part reuses first 64 floats for ve)
  __shared__ float Xc[32 * 64];    // 8 KB (transposed: Xc[k][r])
  const int t = threadIdx.x;
  if (blockIdx.x < nbs) {
    // -------- scatter part --------
    if (t < 64) Wc[t] = v_edge[t];
    __syncthreads();
    int i = blockIdx.x * 256 + t;
    if (i >= E) return;
    int f = *is64;
    int src = f ? ei[2 * i] : ei[i];
    int dst = f ? ei[2 * (E + i)] : ei[E + i];
    float a16[16];
    *(float4*)&a16[0]  = *(const float4*)&edge_attr[(size_t)i * 16];
    *(float4*)&a16[4]  = *(const float4*)&edge_attr[(size_t)i * 16 + 4];
    *(float4*)&a16[8]  = *(const float4*)&edge_attr[(size_t)i * 16 + 8];
    *(float4*)&a16[12] = *(const float4*)&edge_attr[(size_t)i * 16 + 12];
    float ae[4];
#pragma unroll
    for (int h = 0; h < 4; ++h) {
      float s = 0.f;
#pragma unroll
      for (int j = 0; j < 16; ++j) s += a16[j] * Wc[h * 16 + j];
      ae[h] = s;
    }
    int pos = offs[dst] + rank[i];
    __half2 e01 = __floats2half2_rn(ae[0], ae[1]);
    __half2 e23 = __floats2half2_rn(ae[2], ae[3]);
    int4 r; r.x = *(int*)&e01; r.y = *(int*)&e23; r.z = src; r.w = 0;
    rec[pos] = r;
    return;
  }
  // -------- GEMM part --------
  const int tcol = t & 31;         // cols tcol*4 .. +3   (head h = tcol>>3)
  const int trow = t >> 5;         // rows trow*8 .. +7
  const int row0 = (blockIdx.x - nbs) * 64;
  const int r = t & 63, kq = t >> 6;
  const float4 aw_s = *(const float4*)&att_src[tcol * 4];
  const float4 aw_d = *(const float4*)&att_dst[tcol * 4];
  float acc[8][4];
#pragma unroll
  for (int i = 0; i < 8; ++i) { acc[i][0] = acc[i][1] = acc[i][2] = acc[i][3] = 0.f; }

  for (int kc = 0; kc < 4; ++kc) {
    float4 wreg[4];
#pragma unroll
    for (int q = 0; q < 4; ++q) wreg[q] = *(const float4*)&W[kc * 4096 + (q * 256 + t) * 4];
    float xs8[8];
    int grow = row0 + r;
    if (grow < N) {
      *(float4*)&xs8[0] = *(const float4*)&x[grow * 128 + kc * 32 + kq * 8];
      *(float4*)&xs8[4] = *(const float4*)&x[grow * 128 + kc * 32 + kq * 8 + 4];
    } else {
#pragma unroll
      for (int q = 0; q < 8; ++q) xs8[q] = 0.f;
    }
    __syncthreads();   // previous chunk's compute done
#pragma unroll
    for (int q = 0; q < 4; ++q) *(float4*)&Wc[(q * 256 + t) * 4] = wreg[q];
#pragma unroll
    for (int q = 0; q < 8; ++q) Xc[(kq * 8 + q) * 64 + r] = xs8[q];
    __syncthreads();
#pragma unroll
    for (int kk = 0; kk < 32; ++kk) {
      float4 wv = *(const float4*)&Wc[kk * 128 + tcol * 4];
      float xr[8];
      *(float4*)&xr[0] = *(const float4*)&Xc[kk * 64 + trow * 8];
      *(float4*)&xr[4] = *(const float4*)&Xc[kk * 64 + trow * 8 + 4];
#pragma unroll
      for (int ri = 0; ri < 8; ++ri) {
        acc[ri][0] += xr[ri] * wv.x;
        acc[ri][1] += xr[ri] * wv.y;
        acc[ri][2] += xr[ri] * wv.z;
        acc[ri][3] += xr[ri] * wv.w;
      }
    }
  }
#pragma unroll
  for (int ri = 0; ri < 8; ++ri) {
    int grow = row0 + trow * 8 + ri;
    float asp = acc[ri][0] * aw_s.x + acc[ri][1] * aw_s.y + acc[ri][2] * aw_s.z + acc[ri][3] * aw_s.w;
    float adp = acc[ri][0] * aw_d.x + acc[ri][1] * aw_d.y + acc[ri][2] * aw_d.z + acc[ri][3] * aw_d.w;
#pragma unroll
    for (int m = 1; m < 8; m <<= 1) { asp += __shfl_xor(asp, m); adp += __shfl_xor(adp, m); }
    if (grow < N) {
      __half2 h0 = __floats2half2_rn(acc[ri][0], acc[ri][1]);
      __half2 h1 = __floats2half2_rn(acc[ri][2], acc[ri][3]);
      uint2 u; u.x = *(uint_t*)&h0; u.y = *(uint_t*)&h1;
      *(uint2*)&x_l_h[(size_t)grow * 128 + tcol * 4] = u;
      if ((tcol & 7) == 0) {
        a_src[grow * 4 + (tcol >> 3)] = asp;
        a_dst[grow * 4 + (tcol >> 3)] = adp;
      }
    }
  }
}

// ---------------- K34: fused softmax + aggregation, one wave per node, SCALARIZED.
// offs/deg/rec go through readfirstlane -> s_load path; p computed inline from ae.
// Normalization commutes with accumulation: out = (sum p*x + pl*x_node)/(sum p + pl).
// Lane covers cols {2l,2l+1}; h = lane>>4. den/sae lane-redundant within head group.
__global__ __launch_bounds__(256) void k34_agg(
    const int4* __restrict__ rec, const uint_t* __restrict__ xu,
    const float* __restrict__ a_src, const float* __restrict__ a_dst,
    const int* __restrict__ deg, const int* __restrict__ offs,
    const float* __restrict__ bias, float* __restrict__ out, int N) {
  int lane = threadIdx.x & 63;
  int node = blockIdx.x * 4 + (threadIdx.x >> 6);
  if (node >= N) return;
  int offu = __builtin_amdgcn_readfirstlane(offs[node]);
  int dgu  = __builtin_amdgcn_readfirstlane(deg[node]);
  const int4* rp = rec + offu;
  int h = lane >> 4;
  int hs16 = (h & 1) << 4;
  float ad = a_dst[(size_t)node * 4 + h];
  float accx = 0.f, accy = 0.f, den = 0.f, sae = 0.f;
  int i = 0;
  for (; i + 4 <= dgu; i += 4) {
    int4 u0 = rp[i], u1 = rp[i + 1], u2 = rp[i + 2], u3 = rp[i + 3];
    int s0 = __builtin_amdgcn_readfirstlane(u0.z);
    int s1 = __builtin_amdgcn_readfirstlane(u1.z);
    int s2 = __builtin_amdgcn_readfirstlane(u2.z);
    int s3 = __builtin_amdgcn_readfirstlane(u3.z);
    uint_t v0 = xu[((size_t)(uint_t)s0 << 6) + lane];
    uint_t v1 = xu[((size_t)(uint_t)s1 << 6) + lane];
    uint_t v2 = xu[((size_t)(uint_t)s2 << 6) + lane];
    uint_t v3 = xu[((size_t)(uint_t)s3 << 6) + lane];
    float as0 = a_src[((size_t)(uint_t)s0 << 2) + h];
    float as1 = a_src[((size_t)(uint_t)s1 << 2) + h];
    float as2 = a_src[((size_t)(uint_t)s2 << 2) + h];
    float as3 = a_src[((size_t)(uint_t)s3 << 2) + h];
    uint_t w0 = (h & 2) ? (uint_t)u0.y : (uint_t)u0.x;
    uint_t w1 = (h & 2) ? (uint_t)u1.y : (uint_t)u1.x;
    uint_t w2 = (h & 2) ? (uint_t)u2.y : (uint_t)u2.x;
    uint_t w3 = (h & 2) ? (uint_t)u3.y : (uint_t)u3.x;
    float e0 = __half2float(__ushort_as_half((ushort_t)(w0 >> hs16)));
    float e1 = __half2float(__ushort_as_half((ushort_t)(w1 >> hs16)));
    float e2 = __half2float(__ushort_as_half((ushort_t)(w2 >> hs16)));
    float e3 = __half2float(__ushort_as_half((ushort_t)(w3 >> hs16)));
    float g0 = as0 + ad + e0; g0 = fmaxf(g0, NEG_SLOPE * g0);
    float g1 = as1 + ad + e1; g1 = fmaxf(g1, NEG_SLOPE * g1);
    float g2 = as2 + ad + e2; g2 = fmaxf(g2, NEG_SLOPE * g2);
    float g3 = as3 + ad + e3; g3 = fmaxf(g3, NEG_SLOPE * g3);
    float p0 = __expf(g0), p1 = __expf(g1), p2 = __expf(g2), p3 = __expf(g3);
    den += p0 + p1 + p2 + p3;
    sae += e0 + e1 + e2 + e3;
    float2 f0 = __half22float2(*(const __half2*)&v0);
    float2 f1 = __half22float2(*(const __half2*)&v1);
    float2 f2 = __half22float2(*(const __half2*)&v2);
    float2 f3 = __half22float2(*(const __half2*)&v3);
    accx += p0 * f0.x; accy += p0 * f0.y;
    accx += p1 * f1.x; accy += p1 * f1.y;
    accx += p2 * f2.x; accy += p2 * f2.y;
    accx += p3 * f3.x; accy += p3 * f3.y;
  }
  for (; i < dgu; ++i) {
    int4 u = rp[i];
    int s = __builtin_amdgcn_readfirstlane(u.z);
    uint_t v = xu[((size_t)(uint_t)s << 6) + lane];
    float as = a_src[((size_t)(uint_t)s << 2) + h];
    uint_t w = (h & 2) ? (uint_t)u.y : (uint_t)u.x;
    float e = __half2float(__ushort_as_half((ushort_t)(w >> hs16)));
    float g = as + ad + e; g = fmaxf(g, NEG_SLOPE * g);
    float p = __expf(g);
    den += p; sae += e;
    float2 fx = __half22float2(*(const __half2*)&v);
    accx += p * fx.x; accy += p * fx.y;
  }
  // self loop (edge_attr = mean of incoming => a_edge_loop = mean(ae), linearity)
  float asn = a_src[(size_t)node * 4 + h];
  float inv_cnt = 1.f / (float)(dgu > 0 ? dgu : 1);
  float gl = asn + ad + sae * inv_cnt;
  gl = fmaxf(gl, NEG_SLOPE * gl);
  float pl = __expf(gl);
  float iv = 1.f / (den + pl);
  uint_t vn = xu[((size_t)(uint_t)node << 6) + lane];
  float2 fn = __half22float2(*(const __half2*)&vn);
  float2 b2 = *(const float2*)&bias[2 * lane];
  float2 o;
  o.x = (accx + pl * fn.x) * iv + b2.x;
  o.y = (accy + pl * fn.y) * iv + b2.y;
  *(float2*)&out[(size_t)node * 128 + 2 * lane] = o;
}

extern "C" void kernel_launch(void* const* d_in, const int* in_sizes, int n_in,
                              void* d_out, int out_size, void* d_ws, size_t ws_size,
                              hipStream_t stream) {
  const float* x        = (const float*)d_in[0];
  const int*   ei       = (const int*)  d_in[1];
  const float* eattr    = (const float*)d_in[2];
  const float* W        = (const float*)d_in[3];
  const float* W_edge   = (const float*)d_in[4];
  const float* att_src  = (const float*)d_in[5];
  const float* att_dst  = (const float*)d_in[6];
  const float* att_edge = (const float*)d_in[7];
  const float* bias     = (const float*)d_in[8];
  float* out = (float*)d_out;
  const int N = in_sizes[0] / 128;
  const int E = in_sizes[1] / 2;
  (void)n_in; (void)out_size; (void)ws_size;

  char* base = (char*)d_ws;
  size_t off = 0;
  auto take = [&](size_t bytes) -> void* {
    void* p = base + off;
    off = (off + bytes + 255) & ~(size_t)255;
    return p;
  };
  ushort_t* x_l_h = (ushort_t*)take((size_t)N * 128 * 2);
  float* a_src    = (float*)take((size_t)N * 4 * 4);
  float* a_dst    = (float*)take((size_t)N * 4 * 4);
  float* v_edge   = (float*)take(64 * 4);
  int4*  rec      = (int4*)take((size_t)E * 16);       // {ae01, ae23, src, pad}
  int*   deg      = (int*)take((size_t)N * 4);
  int*   offs     = (int*)take((size_t)N * 4);
  int*   rank     = (int*)take((size_t)E * 4);
  int*   bsum     = (int*)take(256 * 4);
  int*   boff     = (int*)take(256 * 4);
  int*   is64     = (int*)take(4);

  const int NB = (N + 1023) / 1024;   // 98 for N=100000 (scan2 supports <=256)
  const int nbs = (E + 255) / 256;    // scatter blocks
  const int nb1 = (N + 63) / 64;      // GEMM blocks

  hipLaunchKernelGGL(k_prep, dim3(2 + (N + 255) / 256), dim3(256), 0, stream,
                     ei, is64, deg, N, W_edge, att_edge, v_edge);
  hipLaunchKernelGGL(k_hist, dim3(nbs), dim3(256), 0, stream, ei, is64, deg, rank, E);
  hipLaunchKernelGGL(k_scan1, dim3(NB), dim3(256), 0, stream, deg, bsum, N);
  hipLaunchKernelGGL(k_scan2, dim3(1), dim3(256), 0, stream, bsum, boff, NB);
  hipLaunchKernelGGL(k_scan3, dim3(NB), dim3(256), 0, stream, deg, boff, offs, N);
  hipLaunchKernelGGL(k1_scatter, dim3(nbs + nb1), dim3(256), 0, stream,
                     x, W, att_src, att_dst, x_l_h, a_src, a_dst, N,
                     ei, is64, rank, offs, eattr, v_edge, rec, E, nbs);
  hipLaunchKernelGGL(k34_agg, dim3((N + 3) / 4), dim3(256), 0, stream,
                     rec, (const uint_t*)x_l_h, a_src, a_dst, deg, offs, bias, out, N);
}